// Round 4
// baseline (288.090 us; speedup 1.0000x reference)
//
#include <hip/hip_runtime.h>
#include <math.h>

#define EMB 512
#define NM 5
#define HID 64
#define NQ 2048
#define NP 256

typedef __attribute__((ext_vector_type(8))) short short8;   // 8 bf16 = 16B
typedef __attribute__((ext_vector_type(4))) short short4s;  // 4 bf16 = 8B
typedef __attribute__((ext_vector_type(4))) float floatx4;
typedef __attribute__((ext_vector_type(4))) float vf4;
typedef __attribute__((ext_vector_type(2))) float vf2;

// ws layout (bytes)
#define A_BY  0u                   // A[m][q][h] f32 (+b1)          2,621,440
#define B_BY  2621440u             // B[m][h/4][p][h%4] f32           327,680
#define WH_BY 2949120u             // W1 hi bf16 [5][64][1024]        655,360
#define WL_BY 3604480u             // W1 lo bf16 [5][64][1024]        655,360
#define QH_BY 4259840u             // Q  hi bf16 [2048][512]        2,097,152
#define PH_BY 6356992u             // P  hi bf16 [256][512]           262,144

#define LST 72                     // LDS row stride in shorts (144B, 16B-aligned)

__device__ inline unsigned short bfr(float f) {            // f32 -> bf16 RNE
    unsigned u = __float_as_uint(f);
    u += 0x7FFFu + ((u >> 16) & 1u);
    return (unsigned short)(u >> 16);
}

// ---------------------------------------------------------------------------
// Kernel 0: one-shot conversion. R16: gemm_v3 spent ~180 VALU/thread/chunk
// re-converting the SAME W1 values in up to 128 blocks (~31 us inferred).
// Convert once here (bit-identical bfr math; MFMA order preserved in gemm ->
// absmax must stay 0.0009765625 exactly).
//   f4 ranges: W1 81920 | Q 262144 | P 32768   -> 376832 = 1472 * 256
__global__ __launch_bounds__(256) void cvt_pre(const float* __restrict__ Q,
                                               const float* __restrict__ P,
                                               const float* __restrict__ W1,
                                               short* __restrict__ WHg,
                                               short* __restrict__ WLg,
                                               short* __restrict__ QHg,
                                               short* __restrict__ PHg) {
    int i = blockIdx.x * 256 + threadIdx.x;
    if (i < 81920) {
        float4 v = ((const float4*)W1)[i];
        short4s hi, lo;
#define C1(I, V) { unsigned short h_ = bfr(V); hi[I] = (short)h_; \
    lo[I] = (short)bfr((V) - __uint_as_float(((unsigned)h_) << 16)); }
        C1(0, v.x) C1(1, v.y) C1(2, v.z) C1(3, v.w)
#undef C1
        ((short4s*)WHg)[i] = hi;
        ((short4s*)WLg)[i] = lo;
    } else if (i < 81920 + 262144) {
        int j = i - 81920;
        float4 v = ((const float4*)Q)[j];
        short4s hi;
        hi[0] = (short)bfr(v.x); hi[1] = (short)bfr(v.y);
        hi[2] = (short)bfr(v.z); hi[3] = (short)bfr(v.w);
        ((short4s*)QHg)[j] = hi;
    } else {
        int j = i - 344064;
        float4 v = ((const float4*)P)[j];
        short4s hi;
        hi[0] = (short)bfr(v.x); hi[1] = (short)bfr(v.y);
        hi[2] = (short)bfr(v.z); hi[3] = (short)bfr(v.w);
        ((short4s*)PHg)[j] = hi;
    }
}

// ---------------------------------------------------------------------------
// Kernel 1: MFMA GEMM — same verified structure/LDS layout/indices as the
// 92.6 us gemm_v3, but staging is now short8 load -> ds_write_b128 of the
// pre-converted bf16 (no in-loop conversion: ~25 instr/chunk vs ~200).
__global__ __launch_bounds__(256) void gemm_v4(const short* __restrict__ WHg,
                                               const short* __restrict__ WLg,
                                               const short* __restrict__ QHg,
                                               const short* __restrict__ PHg,
                                               const float* __restrict__ b1,
                                               float* __restrict__ A,
                                               float* __restrict__ Bv) {
    __shared__ short XH[2][16 * LST];
    __shared__ short WH[2][64 * LST];
    __shared__ short WL[2][64 * LST];

    int tid  = threadIdx.x;
    int lane = tid & 63;
    int ht   = tid >> 6;
    int m    = blockIdx.x % 5;
    int rt   = blockIdx.x / 5;           // 0..143
    int r0   = rt * 16;
    bool isQ = rt < 128;

    int wrow = tid >> 3;                 // 0..31  (also rows +32)
    int wg8  = (tid & 7) * 8;            // k offset (shorts) within 64-chunk
    int off  = isQ ? 0 : 512;
    const short* whp0 = WHg + ((size_t)(m * 64 + wrow)) * 1024 + off + wg8;
    const short* whp1 = whp0 + 32 * 1024;
    const short* wlp0 = WLg + ((size_t)(m * 64 + wrow)) * 1024 + off + wg8;
    const short* wlp1 = wlp0 + 32 * 1024;
    bool hasX = tid < 128;
    int xrow  = tid >> 3;                // 0..15 when hasX
    const short* xp = (isQ ? QHg + (size_t)(r0 + xrow) * 512
                           : PHg + (size_t)(r0 - NQ + xrow) * 512) + wg8;

    int arix = (lane & 15) * LST + (lane >> 4) * 8;
    int brix = (ht * 16 + (lane & 15)) * LST + (lane >> 4) * 8;

    floatx4 ac = {0, 0, 0, 0};
    short8 wh0, wh1, wl0, wl1, xh;

    // prologue: chunk 0 -> buf 0
    wh0 = *(const short8*)&whp0[0]; wh1 = *(const short8*)&whp1[0];
    wl0 = *(const short8*)&wlp0[0]; wl1 = *(const short8*)&wlp1[0];
    if (hasX) xh = *(const short8*)&xp[0];
    *(short8*)&WH[0][wrow * LST + wg8] = wh0;
    *(short8*)&WH[0][(wrow + 32) * LST + wg8] = wh1;
    *(short8*)&WL[0][wrow * LST + wg8] = wl0;
    *(short8*)&WL[0][(wrow + 32) * LST + wg8] = wl1;
    if (hasX) *(short8*)&XH[0][xrow * LST + wg8] = xh;

#pragma unroll 1
    for (int c = 0; c < 8; ++c) {
        int cur = c & 1;
        if (c < 7) {                      // issue loads for c+1 (no wait)
            int k0 = (c + 1) * 64;
            wh0 = *(const short8*)&whp0[k0]; wh1 = *(const short8*)&whp1[k0];
            wl0 = *(const short8*)&wlp0[k0]; wl1 = *(const short8*)&wlp1[k0];
            if (hasX) xh = *(const short8*)&xp[k0];
        }
        __syncthreads();                  // buf[cur] writes done; readers of buf[cur^1] done

#pragma unroll
        for (int s = 0; s < 2; ++s) {     // two 32-k sub-chunks
            short8 Ah = *(const short8*)&XH[cur][arix + s * 32];
            short8 Bh = *(const short8*)&WH[cur][brix + s * 32];
            short8 Bl = *(const short8*)&WL[cur][brix + s * 32];
            ac = __builtin_amdgcn_mfma_f32_16x16x32_bf16(Ah, Bl, ac, 0, 0, 0);
            ac = __builtin_amdgcn_mfma_f32_16x16x32_bf16(Ah, Bh, ac, 0, 0, 0);
        }

        if (c < 7) {                      // store to next buf (vmcnt wait lands here)
            int nb = cur ^ 1;
            *(short8*)&WH[nb][wrow * LST + wg8] = wh0;
            *(short8*)&WH[nb][(wrow + 32) * LST + wg8] = wh1;
            *(short8*)&WL[nb][wrow * LST + wg8] = wl0;
            *(short8*)&WL[nb][(wrow + 32) * LST + wg8] = wl1;
            if (hasX) *(short8*)&XH[nb][xrow * LST + wg8] = xh;
        }
    }

    int col  = lane & 15;
    int rloc = (lane >> 4) * 4;
    int hh   = ht * 16 + col;
    int rr   = r0 + rloc;

    if (isQ) {
        float bb = b1[m * 64 + hh];
        float* dst = &A[((size_t)m * NQ + rr) * HID + hh];
        dst[0 * HID] = ac.x + bb; dst[1 * HID] = ac.y + bb;
        dst[2 * HID] = ac.z + bb; dst[3 * HID] = ac.w + bb;
    } else {
        int p = rr - NQ;
        float* dst = &Bv[(((size_t)(m * 16 + (hh >> 2))) * NP + p) * 4 + (hh & 3)];
        dst[0 * 4] = ac.x; dst[1 * 4] = ac.y; dst[2 * 4] = ac.z; dst[3 * 4] = ac.w;
    }
}

// ---------------------------------------------------------------------------
// Kernel 2: fused relu-ensemble + mean/std/exp.
// R16: R0/R2 both ~21 us because per-CU L1 bytes were identical (~1.3 MB/CU)
// — q-duplication fetches per-lane even when L2 dedups. QT=4: thread owns
// 4 q at full 256-p span -> zero duplication, 0.65 MB/CU. Bc[16]+Bn[16]
// double-buffer = 128 VGPR; __launch_bounds__(256,2) keeps cap at 256 (R1's
// spill was the default 116 cap). A/W2/b2 staged in LDS (block-uniform
// broadcast reads, conflict-free). Grid 512 = 2 blocks/CU = 16 waves/CU.
#define AST 68
__global__ __launch_bounds__(256, 2) void fused_main(const float* __restrict__ A,
                                                     const float* __restrict__ Bv,
                                                     const float* __restrict__ W2,
                                                     const float* __restrict__ b2,
                                                     float* __restrict__ out) {
    __shared__ float As[NM][4][AST];          // 5,440 B
    __shared__ float Ws[NM][HID];             // 1,280 B
    __shared__ float bs[NM];

    int tid = threadIdx.x;
    int p   = tid;                            // 0..255 (full p span)
    int q0  = blockIdx.x * 4;

    {   // stage A slice: 5 x 4 x 16 f4 = 320 f4
        const float4* Ag = (const float4*)A;
        for (int i = tid; i < 320; i += 256) {
            int m = i >> 6, rem = i & 63;
            int qr = rem >> 4, j = rem & 15;
            *(float4*)&As[m][qr][j * 4] =
                Ag[(size_t)m * (NQ * 16) + (size_t)(q0 + qr) * 16 + j];
        }
        if (tid < 80) {                       // W2: 5*64 f32 = 80 f4
            int m = tid >> 4, j = tid & 15;
            *(float4*)&Ws[m][j * 4] = ((const float4*)W2)[tid];
        }
        if (tid < NM) bs[tid] = b2[tid];
    }
    __syncthreads();

    const vf4* Bq = (const vf4*)Bv + p;       // f4 idx (m*16+j)*NP + p

    float s1[4] = {0.f, 0.f, 0.f, 0.f}, s2[4] = {0.f, 0.f, 0.f, 0.f};

    vf4 Bc[16], Bn[16];
#pragma unroll
    for (int j = 0; j < 16; ++j) Bc[j] = Bq[j * NP];      // m=0

#pragma unroll 1
    for (int m = 0; m < NM; ++m) {
        if (m < NM - 1) {                                  // prefetch next m
#pragma unroll
            for (int j = 0; j < 16; ++j) Bn[j] = Bq[((m + 1) * 16 + j) * NP];
        }

#pragma unroll
        for (int qi = 0; qi < 4; ++qi) {
            const float* Ar = &As[m][qi][0];
            vf2 acc = {0.f, 0.f};
#pragma unroll
            for (int j = 0; j < 16; ++j) {
                vf2 a0 = *(const vf2*)&Ar[j * 4 + 0];
                vf2 a1 = *(const vf2*)&Ar[j * 4 + 2];
                vf2 w0 = *(const vf2*)&Ws[m][j * 4 + 0];
                vf2 w1 = *(const vf2*)&Ws[m][j * 4 + 2];
                vf2 z  = {0.f, 0.f};
                vf2 t0 = __builtin_elementwise_max(a0 + Bc[j].xy, z);
                vf2 t1 = __builtin_elementwise_max(a1 + Bc[j].zw, z);
                acc = t0 * w0 + acc;                       // v_pk_fma_f32
                acc = t1 * w1 + acc;
            }
            float x = acc.x + acc.y + bs[m];
            s1[qi] += x;
            s2[qi] = fmaf(x, x, s2[qi]);
        }

        if (m < NM - 1) {
#pragma unroll
            for (int j = 0; j < 16; ++j) Bc[j] = Bn[j];
        }
    }

#pragma unroll
    for (int qi = 0; qi < 4; ++qi) {
        float mean = s1[qi] * 0.2f;
        float var  = fmaxf((s2[qi] - s1[qi] * s1[qi] * 0.2f) * 0.25f, 0.f);
        out[(size_t)(q0 + qi) * NP + p] = mean * __expf(-sqrtf(var));
    }
}

// ---------------------------------------------------------------------------
extern "C" void kernel_launch(void* const* d_in, const int* in_sizes, int n_in,
                              void* d_out, int out_size, void* d_ws, size_t ws_size,
                              hipStream_t stream) {
    const float* Q  = (const float*)d_in[0];   // (2048, 512)
    const float* P  = (const float*)d_in[1];   // (256, 512)
    const float* W1 = (const float*)d_in[2];   // (5, 64, 1024)
    const float* b1 = (const float*)d_in[3];   // (5, 64)
    const float* W2 = (const float*)d_in[4];   // (5, 64)
    const float* b2 = (const float*)d_in[5];   // (5,)
    float* out = (float*)d_out;

    char*  ws  = (char*)d_ws;
    float* A   = (float*)(ws + A_BY);
    float* B   = (float*)(ws + B_BY);
    short* WHg = (short*)(ws + WH_BY);
    short* WLg = (short*)(ws + WL_BY);
    short* QHg = (short*)(ws + QH_BY);
    short* PHg = (short*)(ws + PH_BY);

    cvt_pre<<<1472, 256, 0, stream>>>(Q, P, W1, WHg, WLg, QHg, PHg);
    gemm_v4<<<720, 256, 0, stream>>>(WHg, WLg, QHg, PHg, b1, A, B);
    fused_main<<<512, 256, 0, stream>>>(A, B, W2, b2, out);
}

// Round 5
// 106.418 us; speedup vs baseline: 2.7072x; 2.7072x over previous
//
#include <hip/hip_runtime.h>
#include <math.h>

#define EMB 512
#define NM 5
#define HID 64
#define NQ 2048
#define NP 256

typedef __attribute__((ext_vector_type(8))) short short8;   // 8 bf16 = 16B
typedef __attribute__((ext_vector_type(4))) short short4s;  // 4 bf16 = 8B
typedef __attribute__((ext_vector_type(4))) float floatx4;
typedef __attribute__((ext_vector_type(4))) float vf4;
typedef __attribute__((ext_vector_type(2))) float vf2;

// ws layout (bytes)
#define A_BY  0u                   // A[m][q][h] f32 (+b1)          2,621,440
#define B_BY  2621440u             // B[m][h/4][p][h%4] f32           327,680
#define WH_BY 2949120u             // W1 hi bf16 [5][64][1024]        655,360
#define WL_BY 3604480u             // W1 lo bf16 [5][64][1024]        655,360
#define QH_BY 4259840u             // Q  hi bf16 [2048][512]        2,097,152
#define PH_BY 6356992u             // P  hi bf16 [256][512]           262,144

#define LST 72                     // LDS row stride in shorts (144B, 16B-aligned)

__device__ inline unsigned short bfr(float f) {            // f32 -> bf16 RNE
    unsigned u = __float_as_uint(f);
    u += 0x7FFFu + ((u >> 16) & 1u);
    return (unsigned short)(u >> 16);
}

// ---------------------------------------------------------------------------
// Kernel 0: one-shot conversion (verified R4: cvt+gemm together ~6 us, was
// ~72 us when gemm re-converted W1 per block). Bit-identical bfr math; MFMA
// order preserved in gemm -> absmax stays 0.0009765625 exactly.
//   f4 ranges: W1 81920 | Q 262144 | P 32768   -> 376832 = 1472 * 256
__global__ __launch_bounds__(256) void cvt_pre(const float* __restrict__ Q,
                                               const float* __restrict__ P,
                                               const float* __restrict__ W1,
                                               short* __restrict__ WHg,
                                               short* __restrict__ WLg,
                                               short* __restrict__ QHg,
                                               short* __restrict__ PHg) {
    int i = blockIdx.x * 256 + threadIdx.x;
    if (i < 81920) {
        float4 v = ((const float4*)W1)[i];
        short4s hi, lo;
#define C1(I, V) { unsigned short h_ = bfr(V); hi[I] = (short)h_; \
    lo[I] = (short)bfr((V) - __uint_as_float(((unsigned)h_) << 16)); }
        C1(0, v.x) C1(1, v.y) C1(2, v.z) C1(3, v.w)
#undef C1
        ((short4s*)WHg)[i] = hi;
        ((short4s*)WLg)[i] = lo;
    } else if (i < 81920 + 262144) {
        int j = i - 81920;
        float4 v = ((const float4*)Q)[j];
        short4s hi;
        hi[0] = (short)bfr(v.x); hi[1] = (short)bfr(v.y);
        hi[2] = (short)bfr(v.z); hi[3] = (short)bfr(v.w);
        ((short4s*)QHg)[j] = hi;
    } else {
        int j = i - 344064;
        float4 v = ((const float4*)P)[j];
        short4s hi;
        hi[0] = (short)bfr(v.x); hi[1] = (short)bfr(v.y);
        hi[2] = (short)bfr(v.z); hi[3] = (short)bfr(v.w);
        ((short4s*)PHg)[j] = hi;
    }
}

// ---------------------------------------------------------------------------
// Kernel 1: MFMA GEMM (verified R4, ~4-5 us) — same structure/LDS layout as
// the original verified gemm_v3 but staging pre-converted bf16. UNCHANGED.
__global__ __launch_bounds__(256) void gemm_v4(const short* __restrict__ WHg,
                                               const short* __restrict__ WLg,
                                               const short* __restrict__ QHg,
                                               const short* __restrict__ PHg,
                                               const float* __restrict__ b1,
                                               float* __restrict__ A,
                                               float* __restrict__ Bv) {
    __shared__ short XH[2][16 * LST];
    __shared__ short WH[2][64 * LST];
    __shared__ short WL[2][64 * LST];

    int tid  = threadIdx.x;
    int lane = tid & 63;
    int ht   = tid >> 6;
    int m    = blockIdx.x % 5;
    int rt   = blockIdx.x / 5;           // 0..143
    int r0   = rt * 16;
    bool isQ = rt < 128;

    int wrow = tid >> 3;                 // 0..31  (also rows +32)
    int wg8  = (tid & 7) * 8;            // k offset (shorts) within 64-chunk
    int off  = isQ ? 0 : 512;
    const short* whp0 = WHg + ((size_t)(m * 64 + wrow)) * 1024 + off + wg8;
    const short* whp1 = whp0 + 32 * 1024;
    const short* wlp0 = WLg + ((size_t)(m * 64 + wrow)) * 1024 + off + wg8;
    const short* wlp1 = wlp0 + 32 * 1024;
    bool hasX = tid < 128;
    int xrow  = tid >> 3;                // 0..15 when hasX
    const short* xp = (isQ ? QHg + (size_t)(r0 + xrow) * 512
                           : PHg + (size_t)(r0 - NQ + xrow) * 512) + wg8;

    int arix = (lane & 15) * LST + (lane >> 4) * 8;
    int brix = (ht * 16 + (lane & 15)) * LST + (lane >> 4) * 8;

    floatx4 ac = {0, 0, 0, 0};
    short8 wh0, wh1, wl0, wl1, xh;

    // prologue: chunk 0 -> buf 0
    wh0 = *(const short8*)&whp0[0]; wh1 = *(const short8*)&whp1[0];
    wl0 = *(const short8*)&wlp0[0]; wl1 = *(const short8*)&wlp1[0];
    if (hasX) xh = *(const short8*)&xp[0];
    *(short8*)&WH[0][wrow * LST + wg8] = wh0;
    *(short8*)&WH[0][(wrow + 32) * LST + wg8] = wh1;
    *(short8*)&WL[0][wrow * LST + wg8] = wl0;
    *(short8*)&WL[0][(wrow + 32) * LST + wg8] = wl1;
    if (hasX) *(short8*)&XH[0][xrow * LST + wg8] = xh;

#pragma unroll 1
    for (int c = 0; c < 8; ++c) {
        int cur = c & 1;
        if (c < 7) {                      // issue loads for c+1 (no wait)
            int k0 = (c + 1) * 64;
            wh0 = *(const short8*)&whp0[k0]; wh1 = *(const short8*)&whp1[k0];
            wl0 = *(const short8*)&wlp0[k0]; wl1 = *(const short8*)&wlp1[k0];
            if (hasX) xh = *(const short8*)&xp[k0];
        }
        __syncthreads();                  // buf[cur] writes done; readers of buf[cur^1] done

#pragma unroll
        for (int s = 0; s < 2; ++s) {     // two 32-k sub-chunks
            short8 Ah = *(const short8*)&XH[cur][arix + s * 32];
            short8 Bh = *(const short8*)&WH[cur][brix + s * 32];
            short8 Bl = *(const short8*)&WL[cur][brix + s * 32];
            ac = __builtin_amdgcn_mfma_f32_16x16x32_bf16(Ah, Bl, ac, 0, 0, 0);
            ac = __builtin_amdgcn_mfma_f32_16x16x32_bf16(Ah, Bh, ac, 0, 0, 0);
        }

        if (c < 7) {                      // store to next buf (vmcnt wait lands here)
            int nb = cur ^ 1;
            *(short8*)&WH[nb][wrow * LST + wg8] = wh0;
            *(short8*)&WH[nb][(wrow + 32) * LST + wg8] = wh1;
            *(short8*)&WL[nb][wrow * LST + wg8] = wl0;
            *(short8*)&WL[nb][(wrow + 32) * LST + wg8] = wl1;
            if (hasX) *(short8*)&XH[nb][xrow * LST + wg8] = xh;
        }
    }

    int col  = lane & 15;
    int rloc = (lane >> 4) * 4;
    int hh   = ht * 16 + col;
    int rr   = r0 + rloc;

    if (isQ) {
        float bb = b1[m * 64 + hh];
        float* dst = &A[((size_t)m * NQ + rr) * HID + hh];
        dst[0 * HID] = ac.x + bb; dst[1 * HID] = ac.y + bb;
        dst[2 * HID] = ac.z + bb; dst[3 * HID] = ac.w + bb;
    } else {
        int p = rr - NQ;
        float* dst = &Bv[(((size_t)(m * 16 + (hh >> 2))) * NP + p) * 4 + (hh & 3)];
        dst[0 * 4] = ac.x; dst[1 * 4] = ac.y; dst[2 * 4] = ac.z; dst[3 * 4] = ac.w;
    }
}

// ---------------------------------------------------------------------------
// Kernel 2: fused relu-ensemble + mean/std/exp — v5.
// R4 post-mortem: Bc[16]+Bn[16] (128 data VGPR) spilled to scratch ->
// 736 MB scratch writes -> 282 us. R2 variant (A/W2 in LDS) was LDS-issue
// bound (~640 ds_read_b64/thread ~ 12.8 us/CU). New resource split:
//   A, W2, b2 : uniform scalar loads (addresses depend only on blockIdx/m
//               -> s_load into SGPRs, SMEM pipe, zero VALU/VMEM cost)
//   B         : single Bc[16] vf4 buffer (64 VGPR), reloaded per m; no Bn.
//   math      : pk-fp32; each VALU op has <=1 SGPR operand (legal).
// ~100 VGPR total -> no spill; zero LDS. Grid 512 = 2 blocks/CU = 8 waves.
// Floors: VALU ~3.2 us, B L2 traffic 512x327KB=167MB ~ 4.8 us -> expect ~5-7.
__global__ __launch_bounds__(256, 4) void fused_main(const float* __restrict__ A,
                                                     const float* __restrict__ Bv,
                                                     const float* __restrict__ W2,
                                                     const float* __restrict__ b2,
                                                     float* __restrict__ out) {
    int p  = threadIdx.x;            // 0..255 (full p span)
    int q0 = blockIdx.x * 4;

    const vf4* Bq = (const vf4*)Bv + p;       // f4 idx (m*16+j)*NP + p

    float s1[4] = {0.f, 0.f, 0.f, 0.f}, s2[4] = {0.f, 0.f, 0.f, 0.f};
    vf4 Bc[16];

#pragma unroll 1
    for (int m = 0; m < NM; ++m) {
#pragma unroll
        for (int j = 0; j < 16; ++j) Bc[j] = Bq[(m * 16 + j) * NP];

        const float* Ar = A + ((size_t)m * NQ + q0) * HID;   // uniform -> s_load
        const float* Wm = W2 + m * HID;                      // uniform -> s_load
        float bb = b2[m];                                    // uniform

#pragma unroll
        for (int qi = 0; qi < 4; ++qi) {
            const float* Aq = Ar + qi * HID;
            vf2 acc = {0.f, 0.f};
#pragma unroll
            for (int j = 0; j < 16; ++j) {
                vf2 a0 = *(const vf2*)&Aq[j * 4 + 0];        // SGPR pair
                vf2 a1 = *(const vf2*)&Aq[j * 4 + 2];
                vf2 w0 = *(const vf2*)&Wm[j * 4 + 0];        // SGPR pair
                vf2 w1 = *(const vf2*)&Wm[j * 4 + 2];
                vf2 z  = {0.f, 0.f};
                vf2 t0 = __builtin_elementwise_max(a0 + Bc[j].xy, z);
                vf2 t1 = __builtin_elementwise_max(a1 + Bc[j].zw, z);
                acc = t0 * w0 + acc;                         // v_pk_fma_f32
                acc = t1 * w1 + acc;
            }
            float x = acc.x + acc.y + bb;
            s1[qi] += x;
            s2[qi] = fmaf(x, x, s2[qi]);
        }
    }

#pragma unroll
    for (int qi = 0; qi < 4; ++qi) {
        float mean = s1[qi] * 0.2f;
        float var  = fmaxf((s2[qi] - s1[qi] * s1[qi] * 0.2f) * 0.25f, 0.f);
        out[(size_t)(q0 + qi) * NP + p] = mean * __expf(-sqrtf(var));
    }
}

// ---------------------------------------------------------------------------
extern "C" void kernel_launch(void* const* d_in, const int* in_sizes, int n_in,
                              void* d_out, int out_size, void* d_ws, size_t ws_size,
                              hipStream_t stream) {
    const float* Q  = (const float*)d_in[0];   // (2048, 512)
    const float* P  = (const float*)d_in[1];   // (256, 512)
    const float* W1 = (const float*)d_in[2];   // (5, 64, 1024)
    const float* b1 = (const float*)d_in[3];   // (5, 64)
    const float* W2 = (const float*)d_in[4];   // (5, 64)
    const float* b2 = (const float*)d_in[5];   // (5,)
    float* out = (float*)d_out;

    char*  ws  = (char*)d_ws;
    float* A   = (float*)(ws + A_BY);
    float* B   = (float*)(ws + B_BY);
    short* WHg = (short*)(ws + WH_BY);
    short* WLg = (short*)(ws + WL_BY);
    short* QHg = (short*)(ws + QH_BY);
    short* PHg = (short*)(ws + PH_BY);

    cvt_pre<<<1472, 256, 0, stream>>>(Q, P, W1, WHg, WLg, QHg, PHg);
    gemm_v4<<<720, 256, 0, stream>>>(WHg, WLg, QHg, PHg, b1, A, B);
    fused_main<<<512, 256, 0, stream>>>(A, B, W2, b2, out);
}

// Round 6
// 94.867 us; speedup vs baseline: 3.0368x; 1.1218x over previous
//
#include <hip/hip_runtime.h>
#include <math.h>

#define EMB 512
#define NM 5
#define HID 64
#define NQ 2048
#define NP 256

typedef __attribute__((ext_vector_type(8))) short short8;   // 8 bf16 = 16B
typedef __attribute__((ext_vector_type(4))) short short4s;  // 4 bf16 = 8B
typedef __attribute__((ext_vector_type(4))) float floatx4;
typedef __attribute__((ext_vector_type(4))) float vf4;
typedef __attribute__((ext_vector_type(2))) float vf2;

// ws layout (bytes)
#define A_BY  0u                   // A[m][q][h] f32 (+b1)          2,621,440
#define B_BY  2621440u             // B[m][h/4][p][h%4] f32           327,680
#define WH_BY 2949120u             // W1 hi bf16 [5][64][1024]        655,360
#define WL_BY 3604480u             // W1 lo bf16 [5][64][1024]        655,360
#define QH_BY 4259840u             // Q  hi bf16 [2048][512]        2,097,152
#define PH_BY 6356992u             // P  hi bf16 [256][512]           262,144

#define LST 72                     // LDS row stride in shorts (144B, 16B-aligned)

__device__ inline unsigned short bfr(float f) {            // f32 -> bf16 RNE
    unsigned u = __float_as_uint(f);
    u += 0x7FFFu + ((u >> 16) & 1u);
    return (unsigned short)(u >> 16);
}

// ---------------------------------------------------------------------------
// Kernel 0: one-shot conversion (verified R4: cvt+gemm together ~6 us, was
// ~30 us when gemm re-converted W1 per block). Bit-identical bfr math; MFMA
// order preserved in gemm -> absmax stays 0.0009765625 exactly. UNCHANGED.
__global__ __launch_bounds__(256) void cvt_pre(const float* __restrict__ Q,
                                               const float* __restrict__ P,
                                               const float* __restrict__ W1,
                                               short* __restrict__ WHg,
                                               short* __restrict__ WLg,
                                               short* __restrict__ QHg,
                                               short* __restrict__ PHg) {
    int i = blockIdx.x * 256 + threadIdx.x;
    if (i < 81920) {
        float4 v = ((const float4*)W1)[i];
        short4s hi, lo;
#define C1(I, V) { unsigned short h_ = bfr(V); hi[I] = (short)h_; \
    lo[I] = (short)bfr((V) - __uint_as_float(((unsigned)h_) << 16)); }
        C1(0, v.x) C1(1, v.y) C1(2, v.z) C1(3, v.w)
#undef C1
        ((short4s*)WHg)[i] = hi;
        ((short4s*)WLg)[i] = lo;
    } else if (i < 81920 + 262144) {
        int j = i - 81920;
        float4 v = ((const float4*)Q)[j];
        short4s hi;
        hi[0] = (short)bfr(v.x); hi[1] = (short)bfr(v.y);
        hi[2] = (short)bfr(v.z); hi[3] = (short)bfr(v.w);
        ((short4s*)QHg)[j] = hi;
    } else {
        int j = i - 344064;
        float4 v = ((const float4*)P)[j];
        short4s hi;
        hi[0] = (short)bfr(v.x); hi[1] = (short)bfr(v.y);
        hi[2] = (short)bfr(v.z); hi[3] = (short)bfr(v.w);
        ((short4s*)PHg)[j] = hi;
    }
}

// ---------------------------------------------------------------------------
// Kernel 1: MFMA GEMM (verified R4/R5, ~4 us) — UNCHANGED.
__global__ __launch_bounds__(256) void gemm_v4(const short* __restrict__ WHg,
                                               const short* __restrict__ WLg,
                                               const short* __restrict__ QHg,
                                               const short* __restrict__ PHg,
                                               const float* __restrict__ b1,
                                               float* __restrict__ A,
                                               float* __restrict__ Bv) {
    __shared__ short XH[2][16 * LST];
    __shared__ short WH[2][64 * LST];
    __shared__ short WL[2][64 * LST];

    int tid  = threadIdx.x;
    int lane = tid & 63;
    int ht   = tid >> 6;
    int m    = blockIdx.x % 5;
    int rt   = blockIdx.x / 5;           // 0..143
    int r0   = rt * 16;
    bool isQ = rt < 128;

    int wrow = tid >> 3;                 // 0..31  (also rows +32)
    int wg8  = (tid & 7) * 8;            // k offset (shorts) within 64-chunk
    int off  = isQ ? 0 : 512;
    const short* whp0 = WHg + ((size_t)(m * 64 + wrow)) * 1024 + off + wg8;
    const short* whp1 = whp0 + 32 * 1024;
    const short* wlp0 = WLg + ((size_t)(m * 64 + wrow)) * 1024 + off + wg8;
    const short* wlp1 = wlp0 + 32 * 1024;
    bool hasX = tid < 128;
    int xrow  = tid >> 3;                // 0..15 when hasX
    const short* xp = (isQ ? QHg + (size_t)(r0 + xrow) * 512
                           : PHg + (size_t)(r0 - NQ + xrow) * 512) + wg8;

    int arix = (lane & 15) * LST + (lane >> 4) * 8;
    int brix = (ht * 16 + (lane & 15)) * LST + (lane >> 4) * 8;

    floatx4 ac = {0, 0, 0, 0};
    short8 wh0, wh1, wl0, wl1, xh;

    // prologue: chunk 0 -> buf 0
    wh0 = *(const short8*)&whp0[0]; wh1 = *(const short8*)&whp1[0];
    wl0 = *(const short8*)&wlp0[0]; wl1 = *(const short8*)&wlp1[0];
    if (hasX) xh = *(const short8*)&xp[0];
    *(short8*)&WH[0][wrow * LST + wg8] = wh0;
    *(short8*)&WH[0][(wrow + 32) * LST + wg8] = wh1;
    *(short8*)&WL[0][wrow * LST + wg8] = wl0;
    *(short8*)&WL[0][(wrow + 32) * LST + wg8] = wl1;
    if (hasX) *(short8*)&XH[0][xrow * LST + wg8] = xh;

#pragma unroll 1
    for (int c = 0; c < 8; ++c) {
        int cur = c & 1;
        if (c < 7) {                      // issue loads for c+1 (no wait)
            int k0 = (c + 1) * 64;
            wh0 = *(const short8*)&whp0[k0]; wh1 = *(const short8*)&whp1[k0];
            wl0 = *(const short8*)&wlp0[k0]; wl1 = *(const short8*)&wlp1[k0];
            if (hasX) xh = *(const short8*)&xp[k0];
        }
        __syncthreads();                  // buf[cur] writes done; readers of buf[cur^1] done

#pragma unroll
        for (int s = 0; s < 2; ++s) {     // two 32-k sub-chunks
            short8 Ah = *(const short8*)&XH[cur][arix + s * 32];
            short8 Bh = *(const short8*)&WH[cur][brix + s * 32];
            short8 Bl = *(const short8*)&WL[cur][brix + s * 32];
            ac = __builtin_amdgcn_mfma_f32_16x16x32_bf16(Ah, Bl, ac, 0, 0, 0);
            ac = __builtin_amdgcn_mfma_f32_16x16x32_bf16(Ah, Bh, ac, 0, 0, 0);
        }

        if (c < 7) {                      // store to next buf (vmcnt wait lands here)
            int nb = cur ^ 1;
            *(short8*)&WH[nb][wrow * LST + wg8] = wh0;
            *(short8*)&WH[nb][(wrow + 32) * LST + wg8] = wh1;
            *(short8*)&WL[nb][wrow * LST + wg8] = wl0;
            *(short8*)&WL[nb][(wrow + 32) * LST + wg8] = wl1;
            if (hasX) *(short8*)&XH[nb][xrow * LST + wg8] = xh;
        }
    }

    int col  = lane & 15;
    int rloc = (lane >> 4) * 4;
    int hh   = ht * 16 + col;
    int rr   = r0 + rloc;

    if (isQ) {
        float bb = b1[m * 64 + hh];
        float* dst = &A[((size_t)m * NQ + rr) * HID + hh];
        dst[0 * HID] = ac.x + bb; dst[1 * HID] = ac.y + bb;
        dst[2 * HID] = ac.z + bb; dst[3 * HID] = ac.w + bb;
    } else {
        int p = rr - NQ;
        float* dst = &Bv[(((size_t)(m * 16 + (hh >> 2))) * NP + p) * 4 + (hh & 3)];
        dst[0 * 4] = ac.x; dst[1 * 4] = ac.y; dst[2 * 4] = ac.z; dst[3 * 4] = ac.w;
    }
}

// ---------------------------------------------------------------------------
// Kernel 2: fused relu-ensemble + mean/std/exp — REVERT to the R2-measured
// version (~21 us as part of the verified 93.6 total). R5's s_load variant
// was SMEM-latency bound at 2 blocks/CU (~58 us timed). This one: grid 1024
// = 4 p-tiles(64) x 256 q-tiles(8); 4 blocks/CU = 16 waves/CU; A in LDS
// (stride 68 -> conflict-free); B single Bc[16] reg set, coalescer dedups
// the qg q-duplication (qg in LOW tid bits); pk-fp32 math.
#define AST 68
__global__ __launch_bounds__(256) void fused_main(const float* __restrict__ A,
                                                  const float* __restrict__ Bv,
                                                  const float* __restrict__ W2,
                                                  const float* __restrict__ b2,
                                                  float* __restrict__ out) {
    __shared__ float As[NM][8][AST];          // 10,880 B

    int tid  = threadIdx.x;
    int bp   = (blockIdx.x & 3) * 64;         // p-tile base
    int q0   = (blockIdx.x >> 2) * 8;         // q-tile base
    int p    = tid >> 2;                      // 0..63 within p-tile
    int qg   = tid & 3;                       // 0..3

    // stage A slice: 5 x 8 x 64 floats = 640 float4
    {
        const float4* Ag = (const float4*)A;  // f4 idx (m*NQ+q)*16 + j
        for (int i = tid; i < 640; i += 256) {
            int m = i >> 7, rem = i & 127;
            int qr = rem >> 4, j = rem & 15;
            *(float4*)&As[m][qr][j * 4] =
                Ag[(size_t)m * (NQ * 16) + (size_t)(q0 + qr) * 16 + j];
        }
    }
    __syncthreads();

    const vf4* Bq = (const vf4*)Bv + (bp + p);   // f4 idx (m*16+j)*NP + p

    float s1[2] = {0.f, 0.f}, s2[2] = {0.f, 0.f};

#pragma unroll 1
    for (int m = 0; m < NM; ++m) {
        vf4 Bc[16];
#pragma unroll
        for (int j = 0; j < 16; ++j) Bc[j] = Bq[(m * 16 + j) * NP];

        const float* Wm = W2 + m * HID;           // block-uniform
        float bb = b2[m];

#pragma unroll
        for (int qi = 0; qi < 2; ++qi) {
            const float* Ar = &As[m][qg * 2 + qi][0];
            vf2 acc = {0.f, 0.f};
#pragma unroll
            for (int j = 0; j < 16; ++j) {
                vf2 a0 = *(const vf2*)&Ar[j * 4 + 0];
                vf2 a1 = *(const vf2*)&Ar[j * 4 + 2];
                vf2 w0 = *(const vf2*)&Wm[j * 4 + 0];
                vf2 w1 = *(const vf2*)&Wm[j * 4 + 2];
                vf2 z  = {0.f, 0.f};
                vf2 t0 = __builtin_elementwise_max(a0 + Bc[j].xy, z);
                vf2 t1 = __builtin_elementwise_max(a1 + Bc[j].zw, z);
                acc = t0 * w0 + acc;              // v_pk_fma_f32
                acc = t1 * w1 + acc;
            }
            float x = acc.x + acc.y + bb;
            s1[qi] += x;
            s2[qi] = fmaf(x, x, s2[qi]);
        }
    }

#pragma unroll
    for (int qi = 0; qi < 2; ++qi) {
        float mean = s1[qi] * 0.2f;
        float var  = fmaxf((s2[qi] - s1[qi] * s1[qi] * 0.2f) * 0.25f, 0.f);
        out[(size_t)(q0 + qg * 2 + qi) * NP + bp + p] =
            mean * __expf(-sqrtf(var));
    }
}

// ---------------------------------------------------------------------------
extern "C" void kernel_launch(void* const* d_in, const int* in_sizes, int n_in,
                              void* d_out, int out_size, void* d_ws, size_t ws_size,
                              hipStream_t stream) {
    const float* Q  = (const float*)d_in[0];   // (2048, 512)
    const float* P  = (const float*)d_in[1];   // (256, 512)
    const float* W1 = (const float*)d_in[2];   // (5, 64, 1024)
    const float* b1 = (const float*)d_in[3];   // (5, 64)
    const float* W2 = (const float*)d_in[4];   // (5, 64)
    const float* b2 = (const float*)d_in[5];   // (5,)
    float* out = (float*)d_out;

    char*  ws  = (char*)d_ws;
    float* A   = (float*)(ws + A_BY);
    float* B   = (float*)(ws + B_BY);
    short* WHg = (short*)(ws + WH_BY);
    short* WLg = (short*)(ws + WL_BY);
    short* QHg = (short*)(ws + QH_BY);
    short* PHg = (short*)(ws + PH_BY);

    cvt_pre<<<1472, 256, 0, stream>>>(Q, P, W1, WHg, WLg, QHg, PHg);
    gemm_v4<<<720, 256, 0, stream>>>(WHg, WLg, QHg, PHg, b1, A, B);
    fused_main<<<1024, 256, 0, stream>>>(A, B, W2, b2, out);
}